// Round 16
// baseline (164.323 us; speedup 1.0000x reference)
//
#include <hip/hip_runtime.h>
#include <hip/hip_bf16.h>
#include <stdint.h>

#define D_ 1024
#define NSEQ 2048

typedef __attribute__((ext_vector_type(8))) short bf16x8;
typedef __attribute__((ext_vector_type(4))) float f32x4;

static __device__ __forceinline__ unsigned short f2bf(float x) {
    union { __hip_bfloat16 h; unsigned short u; } cv;
    cv.h = __float2bfloat16(x);
    return cv.u;
}

// async global->LDS, 16B per lane. LDS dest = wave-uniform base + lane*16 (HW).
static __device__ __forceinline__ void gload_lds16(const void* g, void* l) {
    __builtin_amdgcn_global_load_lds(
        (const __attribute__((address_space(1))) unsigned int*)(uintptr_t)g,
        (__attribute__((address_space(3))) unsigned int*)(uintptr_t)l, 16, 0, 0);
}

// ---------------- prep: x fp32->bf16 (blocks 0..8191) + W transpose->Wt bf16 (blocks 8192..11263) ----------------
__global__ __launch_bounds__(256) void prep(const float* __restrict__ x,
                                            const float* __restrict__ Wq,
                                            const float* __restrict__ Wk,
                                            const float* __restrict__ Wv,
                                            __hip_bfloat16* __restrict__ xb,
                                            __hip_bfloat16* __restrict__ Wt) {
    __shared__ float tile[32][33];
    const int b = blockIdx.x;
    const int t = threadIdx.x;
    if (b < 8192) {
        int i = b * 256 + t;
        float4 v = reinterpret_cast<const float4*>(x)[i];
        ushort4 o;
        o.x = f2bf(v.x); o.y = f2bf(v.y); o.z = f2bf(v.z); o.w = f2bf(v.w);
        reinterpret_cast<ushort4*>(xb)[i] = o;
        return;
    }
    const int b2 = b - 8192;                 // 0..3071
    const int z = b2 >> 10, rem = b2 & 1023; // z: which weight
    const int cx = rem & 31, cy = rem >> 5;  // 32x32 tile grid
    const float* W = (z == 0) ? Wq : (z == 1) ? Wk : Wv;
    unsigned short* O = (unsigned short*)(Wt + (size_t)z * D_ * D_);
    int r0 = cy * 32, c0 = cx * 32;
    int r = t >> 3, c4 = (t & 7) * 4;
    float4 v = *reinterpret_cast<const float4*>(&W[(size_t)(r0 + r) * D_ + c0 + c4]);
    tile[r][c4 + 0] = v.x; tile[r][c4 + 1] = v.y;
    tile[r][c4 + 2] = v.z; tile[r][c4 + 3] = v.w;
    __syncthreads();
    int er = t >> 3, dc = (t & 7) * 4;
    ushort4 pk;
    pk.x = f2bf(tile[dc + 0][er]); pk.y = f2bf(tile[dc + 1][er]);
    pk.z = f2bf(tile[dc + 2][er]); pk.w = f2bf(tile[dc + 3][er]);
    *reinterpret_cast<ushort4*>(&O[(size_t)(c0 + er) * D_ + r0 + dc]) = pk;
}

// ================= QKV: 256x128 tile, BK=64, 8 waves (4M x 2N), triple-buffered =================
// r8 structure (best measured across r8-r14): single barrier + counted vmcnt(6) per K-step,
// vmcnt(0) only last iter. XOR swizzle both-sides (rule #21).
// Grid (24, 32) BY-INNER: consecutive ids share the A panel and sweep B -> first-round
// working set 11.5 MB (Wt fully resident) instead of 18 MB.
__global__ __launch_bounds__(512, 2) void gemm_qkv(
    const __hip_bfloat16* __restrict__ A,   // Xb [8192][1024]
    const __hip_bfloat16* __restrict__ Bt,  // Wt [3072][1024]
    void* __restrict__ q_out, void* __restrict__ k_out, void* __restrict__ vt_out) {
    constexpr int NT = 16;                  // K = 1024 / BK = 64
    extern __shared__ char lds[];           // 147456 B

    const int m0 = blockIdx.y * 256, n0 = blockIdx.x * 128;
    const int tid = threadIdx.x, lane = tid & 63, wid = tid >> 6;
    const int wm = wid >> 1, wn = wid & 1;
    const int lr = lane & 15, lk = lane >> 4;

    const __hip_bfloat16* Apan = A + (size_t)m0 * 1024;
    const __hip_bfloat16* Bpan = Bt + (size_t)n0 * 1024;

    // staging source pointers (pre-swizzled global column), advanced +64/tile
    const __hip_bfloat16* asrc[4];
    const __hip_bfloat16* bsrc[2];
#pragma unroll
    for (int r = 0; r < 4; ++r) {
        const int c = (wid * 4 + r) * 64 + lane;         // chunk in A tile (2048 chunks)
        const int row = c >> 3, slot = c & 7;
        asrc[r] = Apan + (size_t)row * 1024 + (slot ^ (row & 7)) * 8;
    }
#pragma unroll
    for (int r = 0; r < 2; ++r) {
        const int c = (wid * 2 + r) * 64 + lane;         // chunk in B tile (1024 chunks)
        const int row = c >> 3, slot = c & 7;
        bsrc[r] = Bpan + (size_t)row * 1024 + (slot ^ (row & 7)) * 8;
    }

    auto stage = [&](int s) {
        char* base = lds + (s % 3) * 49152;
#pragma unroll
        for (int r = 0; r < 4; ++r) {
            gload_lds16(asrc[r], base + (wid * 4 + r) * 1024);
            asrc[r] += 64;
        }
#pragma unroll
        for (int r = 0; r < 2; ++r) {
            gload_lds16(bsrc[r], base + 32768 + (wid * 2 + r) * 1024);
            bsrc[r] += 64;
        }
    };

    // read-side swizzled slot offsets (per-lane constants)
    const int sw = lr & 7;
    const int slot0 = (lk ^ sw) * 16, slot1 = ((4 + lk) ^ sw) * 16;

    f32x4 acc[4][4] = {};

    stage(0); stage(1);   // 12 loads/wave in flight

    for (int t = 0; t < NT; ++t) {
        if (t >= NT - 1) asm volatile("s_waitcnt vmcnt(0)" ::: "memory");
        else             asm volatile("s_waitcnt vmcnt(6)" ::: "memory");
        __builtin_amdgcn_s_barrier();     // all waves done reading buf[(t+2)%3]'s old tile
        if (t + 2 < NT) stage(t + 2);

        const char* Ab = lds + (t % 3) * 49152;
        const char* Bb = Ab + 32768;
        bf16x8 af0[4], af1[4], bf0[4], bf1[4];
#pragma unroll
        for (int m = 0; m < 4; ++m) {
            const int ra = (wm * 64 + m * 16 + lr) * 128;   // A row byte offset (128B rows)
            const int rb = (wn * 64 + m * 16 + lr) * 128;
            af0[m] = *reinterpret_cast<const bf16x8*>(Ab + ra + slot0);
            af1[m] = *reinterpret_cast<const bf16x8*>(Ab + ra + slot1);
            bf0[m] = *reinterpret_cast<const bf16x8*>(Bb + rb + slot0);
            bf1[m] = *reinterpret_cast<const bf16x8*>(Bb + rb + slot1);
        }
        __builtin_amdgcn_s_setprio(1);
#pragma unroll
        for (int m = 0; m < 4; ++m)
#pragma unroll
            for (int n = 0; n < 4; ++n)
                acc[m][n] = __builtin_amdgcn_mfma_f32_16x16x32_bf16(af0[m], bf0[n], acc[m][n], 0, 0, 0);
#pragma unroll
        for (int m = 0; m < 4; ++m)
#pragma unroll
            for (int n = 0; n < 4; ++n)
                acc[m][n] = __builtin_amdgcn_mfma_f32_16x16x32_bf16(af1[m], bf1[n], acc[m][n], 0, 0, 0);
        __builtin_amdgcn_s_setprio(0);
    }

    // epilogue: route Q / K / Vt by output-column segment
#pragma unroll
    for (int m = 0; m < 4; ++m)
#pragma unroll
        for (int n = 0; n < 4; ++n) {
            const int rbase = m0 + wm * 64 + m * 16 + lk * 4;
            const int cbase = n0 + wn * 64 + n * 16 + lr;
            const int seg = cbase >> 10, e = cbase & 1023;
            if (seg < 2) {
                unsigned short* C = (unsigned short*)(seg == 0 ? q_out : k_out);
#pragma unroll
                for (int j = 0; j < 4; ++j)
                    C[(size_t)(rbase + j) * D_ + e] = f2bf(acc[m][n][j]);
            } else {
                unsigned short* Vt = (unsigned short*)vt_out;
                const int b = rbase >> 11, nq = rbase & 2047;
                ushort4 pk;
                pk.x = f2bf(acc[m][n][0]); pk.y = f2bf(acc[m][n][1]);
                pk.z = f2bf(acc[m][n][2]); pk.w = f2bf(acc[m][n][3]);
                *reinterpret_cast<ushort4*>(&Vt[(((size_t)b << 10) + e) * NSEQ + nq]) = pk;
            }
        }
}

// ---------------- NT GEMM, 128x128 tile, BK=64, 4 waves (2x2), swizzled LDS ----------------
// MODE 2: scores -> P = exp(s*scale) bf16 (masked->0, max-free) + partial row sums -> Pl.
//         Flat 544 lower-tri grid.
// MODE 3: PV; flat 512 grid, anti-correlated Kdim pairing; rinv computed in-block from Pl.
template <int MODE>
__global__ __launch_bounds__(256) void gemm128(const __hip_bfloat16* __restrict__ A, int lda,
                                               const __hip_bfloat16* __restrict__ Bt, int ldb,
                                               void* __restrict__ o0, void* __restrict__ o1,
                                               const float* __restrict__ Pl_in) {
    int bx, by, bz;
    if (MODE == 2) {
        const int fid = blockIdx.x;            // 0..543
        bz = fid & 3;
        const int t = fid >> 2;                // 0..135 triangular index
        bx = (int)((sqrtf(8.0f * t + 1.0f) - 1.0f) * 0.5f);
        while ((bx + 1) * (bx + 2) / 2 <= t) ++bx;
        while (bx * (bx + 1) / 2 > t) --bx;
        by = t - bx * (bx + 1) / 2;            // by <= bx guaranteed
    } else {
        const int fid = blockIdx.x;            // 0..511
        const int bxr = fid & 15;
        bx = (fid & 256) ? 15 - bxr : bxr;     // CU c gets bx and 15-bx -> uniform load
        bz = (fid >> 4) & 3;
        by = fid >> 6;                         // 0..7
    }

    const __hip_bfloat16* Ab = A;
    const __hip_bfloat16* Bb = Bt;
    int Kdim = 1024;
    if (MODE == 2) { Ab += (size_t)bz * NSEQ * lda; Bb += (size_t)bz * NSEQ * ldb; }
    if (MODE == 3) { Ab += (size_t)bz * NSEQ * lda; Bb += (size_t)bz * D_ * ldb; Kdim = (bx + 1) * 128; }

    const int m0 = bx * 128, n0 = by * 128;

    __shared__ __hip_bfloat16 As[128 * 64];   // [128][64], 128B rows, swizzled content
    __shared__ __hip_bfloat16 Bs[128 * 64];
    __shared__ float rinv_lds[128];

    const int tid = threadIdx.x;
    const int lane = tid & 63, wid = tid >> 6;
    const int wm = wid >> 1, wn = wid & 1;
    const int lr = lane & 15, lk = lane >> 4;

    // MODE 3 prologue: per-block rinv for the 128 rows (fused former sum_merge).
    // Visibility to epilogue is guaranteed by the K-loop's __syncthreads (Kdim >= 128).
    if (MODE == 3 && tid < 128) {
        const int q = m0 + tid;
        const int nc = 2 * ((q >> 7) + 1);
        float l = 0.f;
        for (int c = 0; c < nc; ++c) l += Pl_in[(size_t)(bz * NSEQ + q) * 32 + c];
        rinv_lds[tid] = 1.0f / l;
    }

    const __hip_bfloat16* asrc[4];
    const __hip_bfloat16* bsrc[4];
#pragma unroll
    for (int r = 0; r < 4; ++r) {
        const int chunk = r * 256 + tid;
        const int row = chunk >> 3, slot = chunk & 7;
        const int col = ((slot ^ (row & 7)) * 8);
        asrc[r] = Ab + (size_t)(m0 + row) * lda + col;
        bsrc[r] = Bb + (size_t)(n0 + row) * ldb + col;
    }

    const int sw = lr & 7;
    const int slotA0 = (lk ^ sw) * 16, slotA1 = ((4 + lk) ^ sw) * 16;

    f32x4 acc[4][4] = {};

    for (int k0 = 0; k0 < Kdim; k0 += 64) {
#pragma unroll
        for (int r = 0; r < 4; ++r) {
            gload_lds16(asrc[r], (char*)As + r * 4096 + wid * 1024);
            gload_lds16(bsrc[r], (char*)Bs + r * 4096 + wid * 1024);
            asrc[r] += 64; bsrc[r] += 64;
        }
        __syncthreads();

        bf16x8 af0[4], bf0[4], af1[4], bf1[4];
#pragma unroll
        for (int m = 0; m < 4; ++m) {
            const int ra = (wm * 64 + m * 16 + lr) * 128;
            const int rb = (wn * 64 + m * 16 + lr) * 128;
            af0[m] = *reinterpret_cast<const bf16x8*>((const char*)As + ra + slotA0);
            af1[m] = *reinterpret_cast<const bf16x8*>((const char*)As + ra + slotA1);
            bf0[m] = *reinterpret_cast<const bf16x8*>((const char*)Bs + rb + slotA0);
            bf1[m] = *reinterpret_cast<const bf16x8*>((const char*)Bs + rb + slotA1);
        }
#pragma unroll
        for (int m = 0; m < 4; ++m)
#pragma unroll
            for (int n = 0; n < 4; ++n)
                acc[m][n] = __builtin_amdgcn_mfma_f32_16x16x32_bf16(af0[m], bf0[n], acc[m][n], 0, 0, 0);
#pragma unroll
        for (int m = 0; m < 4; ++m)
#pragma unroll
            for (int n = 0; n < 4; ++n)
                acc[m][n] = __builtin_amdgcn_mfma_f32_16x16x32_bf16(af1[m], bf1[n], acc[m][n], 0, 0, 0);
        __syncthreads();
    }

    if (MODE == 2) {
        // max-free softmax numerator: p = exp(s/32) (causal-masked -> 0), stored bf16
        unsigned short* P = (unsigned short*)o0 + (size_t)bz * NSEQ * NSEQ;
#pragma unroll
        for (int m = 0; m < 4; ++m)
#pragma unroll
            for (int n = 0; n < 4; ++n) {
                const int rbase = m0 + wm * 64 + m * 16 + lk * 4;
                const int cbase = n0 + wn * 64 + n * 16 + lr;
#pragma unroll
                for (int j = 0; j < 4; ++j) {
                    float p = (cbase > rbase + j) ? 0.0f
                              : __expf(acc[m][n][j] * 0.03125f);   // 1/sqrt(1024)
                    acc[m][n][j] = p;
                    P[(size_t)(rbase + j) * NSEQ + cbase] = f2bf(p);
                }
            }
        // per-(row, 64-col slice) partial row sums; slice index = by*2 + wn
        float* Pl = (float*)o1;
        const int pcol = by * 2 + wn;
#pragma unroll
        for (int m = 0; m < 4; ++m)
#pragma unroll
            for (int j = 0; j < 4; ++j) {
                float sm = (acc[m][0][j] + acc[m][1][j]) + (acc[m][2][j] + acc[m][3][j]);
#pragma unroll
                for (int w = 1; w < 16; w <<= 1) sm += __shfl_xor(sm, w, 64);
                if (lr == 0) {
                    const int row = bz * NSEQ + m0 + wm * 64 + m * 16 + lk * 4 + j;
                    Pl[row * 32 + pcol] = sm;
                }
            }
    } else {
        float* O = (float*)o0 + (size_t)bz * NSEQ * D_;
#pragma unroll
        for (int m = 0; m < 4; ++m)
#pragma unroll
            for (int n = 0; n < 4; ++n) {
                const int rbase = m0 + wm * 64 + m * 16 + lk * 4;
                const int cbase = n0 + wn * 64 + n * 16 + lr;
#pragma unroll
                for (int j = 0; j < 4; ++j)
                    O[(size_t)(rbase + j) * D_ + cbase] =
                        acc[m][n][j] * rinv_lds[rbase + j - m0];
            }
    }
}

extern "C" void kernel_launch(void* const* d_in, const int* in_sizes, int n_in,
                              void* d_out, int out_size, void* d_ws, size_t ws_size,
                              hipStream_t stream) {
    const float* x  = (const float*)d_in[0];
    const float* Wq = (const float*)d_in[1];
    const float* Wk = (const float*)d_in[2];
    const float* Wv = (const float*)d_in[3];

    char* ws = (char*)d_ws;
    unsigned short* P    = (unsigned short*)(ws);               // 32 MiB (bf16)
    __hip_bfloat16* Xb   = (__hip_bfloat16*)(ws + 67108864);    // 16 MiB (dead after QKV)
    __hip_bfloat16* Q    = (__hip_bfloat16*)(ws + 83886080);    // 16 MiB
    __hip_bfloat16* K    = (__hip_bfloat16*)(ws + 100663296);   // 16 MiB
    __hip_bfloat16* Vt   = (__hip_bfloat16*)(ws + 117440512);   // 16 MiB
    __hip_bfloat16* Wt   = (__hip_bfloat16*)(ws + 134217728);   // 6 MiB
    float*  Pl = (float*)(ws + 67108864);                       // 1 MiB (overlays Xb)

    // fused prep: x->bf16 (8192 blocks) + W transpose (3072 blocks)
    prep<<<11264, 256, 0, stream>>>(x, Wq, Wk, Wv, Xb, Wt);

    // fused QKV: 256x128 triple-buffered pipeline (r8 structure), by-inner grid
    gemm_qkv<<<dim3(24, 32), 512, 147456, stream>>>(Xb, Wt, Q, K, Vt);

    // scores -> P = exp(s/32) + partial row sums (flat lower-triangle enumeration)
    gemm128<2><<<dim3(544), 256, 0, stream>>>(Q, 1024, K, 1024, P, Pl, nullptr);
    // PV (flat grid, anti-correlated Kdim pairing); A = P bf16 (lda 2048);
    // rinv computed per-block from Pl (sum_merge fused away)
    gemm128<3><<<dim3(512), 256, 0, stream>>>((const __hip_bfloat16*)P, 2048, Vt, 2048,
                                              d_out, nullptr, Pl);
}

// Round 17
// 161.503 us; speedup vs baseline: 1.0175x; 1.0175x over previous
//
#include <hip/hip_runtime.h>
#include <hip/hip_bf16.h>
#include <stdint.h>

#define D_ 1024
#define NSEQ 2048

typedef __attribute__((ext_vector_type(8))) short bf16x8;
typedef __attribute__((ext_vector_type(4))) float f32x4;

static __device__ __forceinline__ unsigned short f2bf(float x) {
    union { __hip_bfloat16 h; unsigned short u; } cv;
    cv.h = __float2bfloat16(x);
    return cv.u;
}

// async global->LDS, 16B per lane. LDS dest = wave-uniform base + lane*16 (HW).
static __device__ __forceinline__ void gload_lds16(const void* g, void* l) {
    __builtin_amdgcn_global_load_lds(
        (const __attribute__((address_space(1))) unsigned int*)(uintptr_t)g,
        (__attribute__((address_space(3))) unsigned int*)(uintptr_t)l, 16, 0, 0);
}

// ---------------- prep: x fp32->bf16 (blocks 0..8191) + W transpose->Wt bf16 (blocks 8192..11263) ----------------
__global__ __launch_bounds__(256) void prep(const float* __restrict__ x,
                                            const float* __restrict__ Wq,
                                            const float* __restrict__ Wk,
                                            const float* __restrict__ Wv,
                                            __hip_bfloat16* __restrict__ xb,
                                            __hip_bfloat16* __restrict__ Wt) {
    __shared__ float tile[32][33];
    const int b = blockIdx.x;
    const int t = threadIdx.x;
    if (b < 8192) {
        int i = b * 256 + t;
        float4 v = reinterpret_cast<const float4*>(x)[i];
        ushort4 o;
        o.x = f2bf(v.x); o.y = f2bf(v.y); o.z = f2bf(v.z); o.w = f2bf(v.w);
        reinterpret_cast<ushort4*>(xb)[i] = o;
        return;
    }
    const int b2 = b - 8192;                 // 0..3071
    const int z = b2 >> 10, rem = b2 & 1023; // z: which weight
    const int cx = rem & 31, cy = rem >> 5;  // 32x32 tile grid
    const float* W = (z == 0) ? Wq : (z == 1) ? Wk : Wv;
    unsigned short* O = (unsigned short*)(Wt + (size_t)z * D_ * D_);
    int r0 = cy * 32, c0 = cx * 32;
    int r = t >> 3, c4 = (t & 7) * 4;
    float4 v = *reinterpret_cast<const float4*>(&W[(size_t)(r0 + r) * D_ + c0 + c4]);
    tile[r][c4 + 0] = v.x; tile[r][c4 + 1] = v.y;
    tile[r][c4 + 2] = v.z; tile[r][c4 + 3] = v.w;
    __syncthreads();
    int er = t >> 3, dc = (t & 7) * 4;
    ushort4 pk;
    pk.x = f2bf(tile[dc + 0][er]); pk.y = f2bf(tile[dc + 1][er]);
    pk.z = f2bf(tile[dc + 2][er]); pk.w = f2bf(tile[dc + 3][er]);
    *reinterpret_cast<ushort4*>(&O[(size_t)(c0 + er) * D_ + r0 + dc]) = pk;
}

// ================= QKV: 256x128 tile, BK=64, 8 waves (4M x 2N), triple-buffered =================
// r8 structure (best measured across r8-r16): plain dim3(32,24) BX-INNER grid (768 = 3 exact
// rounds; by-inner raised FETCH 49->79 MB, r16), single barrier + counted vmcnt(6) per K-step,
// vmcnt(0) only last iter. XOR swizzle both-sides (rule #21).
__global__ __launch_bounds__(512, 2) void gemm_qkv(
    const __hip_bfloat16* __restrict__ A,   // Xb [8192][1024]
    const __hip_bfloat16* __restrict__ Bt,  // Wt [3072][1024]
    void* __restrict__ q_out, void* __restrict__ k_out, void* __restrict__ vt_out) {
    constexpr int NT = 16;                  // K = 1024 / BK = 64
    extern __shared__ char lds[];           // 147456 B

    const int m0 = blockIdx.x * 256, n0 = blockIdx.y * 128;
    const int tid = threadIdx.x, lane = tid & 63, wid = tid >> 6;
    const int wm = wid >> 1, wn = wid & 1;
    const int lr = lane & 15, lk = lane >> 4;

    const __hip_bfloat16* Apan = A + (size_t)m0 * 1024;
    const __hip_bfloat16* Bpan = Bt + (size_t)n0 * 1024;

    // staging source pointers (pre-swizzled global column), advanced +64/tile
    const __hip_bfloat16* asrc[4];
    const __hip_bfloat16* bsrc[2];
#pragma unroll
    for (int r = 0; r < 4; ++r) {
        const int c = (wid * 4 + r) * 64 + lane;         // chunk in A tile (2048 chunks)
        const int row = c >> 3, slot = c & 7;
        asrc[r] = Apan + (size_t)row * 1024 + (slot ^ (row & 7)) * 8;
    }
#pragma unroll
    for (int r = 0; r < 2; ++r) {
        const int c = (wid * 2 + r) * 64 + lane;         // chunk in B tile (1024 chunks)
        const int row = c >> 3, slot = c & 7;
        bsrc[r] = Bpan + (size_t)row * 1024 + (slot ^ (row & 7)) * 8;
    }

    auto stage = [&](int s) {
        char* base = lds + (s % 3) * 49152;
#pragma unroll
        for (int r = 0; r < 4; ++r) {
            gload_lds16(asrc[r], base + (wid * 4 + r) * 1024);
            asrc[r] += 64;
        }
#pragma unroll
        for (int r = 0; r < 2; ++r) {
            gload_lds16(bsrc[r], base + 32768 + (wid * 2 + r) * 1024);
            bsrc[r] += 64;
        }
    };

    // read-side swizzled slot offsets (per-lane constants)
    const int sw = lr & 7;
    const int slot0 = (lk ^ sw) * 16, slot1 = ((4 + lk) ^ sw) * 16;

    f32x4 acc[4][4] = {};

    stage(0); stage(1);   // 12 loads/wave in flight

    for (int t = 0; t < NT; ++t) {
        if (t >= NT - 1) asm volatile("s_waitcnt vmcnt(0)" ::: "memory");
        else             asm volatile("s_waitcnt vmcnt(6)" ::: "memory");
        __builtin_amdgcn_s_barrier();     // all waves done reading buf[(t+2)%3]'s old tile
        if (t + 2 < NT) stage(t + 2);

        const char* Ab = lds + (t % 3) * 49152;
        const char* Bb = Ab + 32768;
        bf16x8 af0[4], af1[4], bf0[4], bf1[4];
#pragma unroll
        for (int m = 0; m < 4; ++m) {
            const int ra = (wm * 64 + m * 16 + lr) * 128;   // A row byte offset (128B rows)
            const int rb = (wn * 64 + m * 16 + lr) * 128;
            af0[m] = *reinterpret_cast<const bf16x8*>(Ab + ra + slot0);
            af1[m] = *reinterpret_cast<const bf16x8*>(Ab + ra + slot1);
            bf0[m] = *reinterpret_cast<const bf16x8*>(Bb + rb + slot0);
            bf1[m] = *reinterpret_cast<const bf16x8*>(Bb + rb + slot1);
        }
        __builtin_amdgcn_s_setprio(1);
#pragma unroll
        for (int m = 0; m < 4; ++m)
#pragma unroll
            for (int n = 0; n < 4; ++n)
                acc[m][n] = __builtin_amdgcn_mfma_f32_16x16x32_bf16(af0[m], bf0[n], acc[m][n], 0, 0, 0);
#pragma unroll
        for (int m = 0; m < 4; ++m)
#pragma unroll
            for (int n = 0; n < 4; ++n)
                acc[m][n] = __builtin_amdgcn_mfma_f32_16x16x32_bf16(af1[m], bf1[n], acc[m][n], 0, 0, 0);
        __builtin_amdgcn_s_setprio(0);
    }

    // epilogue: route Q / K / Vt by output-column segment
#pragma unroll
    for (int m = 0; m < 4; ++m)
#pragma unroll
        for (int n = 0; n < 4; ++n) {
            const int rbase = m0 + wm * 64 + m * 16 + lk * 4;
            const int cbase = n0 + wn * 64 + n * 16 + lr;
            const int seg = cbase >> 10, e = cbase & 1023;
            if (seg < 2) {
                unsigned short* C = (unsigned short*)(seg == 0 ? q_out : k_out);
#pragma unroll
                for (int j = 0; j < 4; ++j)
                    C[(size_t)(rbase + j) * D_ + e] = f2bf(acc[m][n][j]);
            } else {
                unsigned short* Vt = (unsigned short*)vt_out;
                const int b = rbase >> 11, nq = rbase & 2047;
                ushort4 pk;
                pk.x = f2bf(acc[m][n][0]); pk.y = f2bf(acc[m][n][1]);
                pk.z = f2bf(acc[m][n][2]); pk.w = f2bf(acc[m][n][3]);
                *reinterpret_cast<ushort4*>(&Vt[(((size_t)b << 10) + e) * NSEQ + nq]) = pk;
            }
        }
}

// ---------------- NT GEMM, 128x128 tile, BK=64, 4 waves (2x2), swizzled LDS ----------------
// MODE 2: scores -> P = exp(s*scale) bf16 (masked->0, max-free) + partial row sums -> Pl.
//         Flat 544 lower-tri grid.
// MODE 3: PV; flat 512 grid, anti-correlated Kdim pairing; rinv computed in-block from Pl.
template <int MODE>
__global__ __launch_bounds__(256) void gemm128(const __hip_bfloat16* __restrict__ A, int lda,
                                               const __hip_bfloat16* __restrict__ Bt, int ldb,
                                               void* __restrict__ o0, void* __restrict__ o1,
                                               const float* __restrict__ Pl_in) {
    int bx, by, bz;
    if (MODE == 2) {
        const int fid = blockIdx.x;            // 0..543
        bz = fid & 3;
        const int t = fid >> 2;                // 0..135 triangular index
        bx = (int)((sqrtf(8.0f * t + 1.0f) - 1.0f) * 0.5f);
        while ((bx + 1) * (bx + 2) / 2 <= t) ++bx;
        while (bx * (bx + 1) / 2 > t) --bx;
        by = t - bx * (bx + 1) / 2;            // by <= bx guaranteed
    } else {
        const int fid = blockIdx.x;            // 0..511
        const int bxr = fid & 15;
        bx = (fid & 256) ? 15 - bxr : bxr;     // CU c gets bx and 15-bx -> uniform load
        bz = (fid >> 4) & 3;
        by = fid >> 6;                         // 0..7
    }

    const __hip_bfloat16* Ab = A;
    const __hip_bfloat16* Bb = Bt;
    int Kdim = 1024;
    if (MODE == 2) { Ab += (size_t)bz * NSEQ * lda; Bb += (size_t)bz * NSEQ * ldb; }
    if (MODE == 3) { Ab += (size_t)bz * NSEQ * lda; Bb += (size_t)bz * D_ * ldb; Kdim = (bx + 1) * 128; }

    const int m0 = bx * 128, n0 = by * 128;

    __shared__ __hip_bfloat16 As[128 * 64];   // [128][64], 128B rows, swizzled content
    __shared__ __hip_bfloat16 Bs[128 * 64];
    __shared__ float rinv_lds[128];

    const int tid = threadIdx.x;
    const int lane = tid & 63, wid = tid >> 6;
    const int wm = wid >> 1, wn = wid & 1;
    const int lr = lane & 15, lk = lane >> 4;

    // MODE 3 prologue: per-block rinv for the 128 rows (fused former sum_merge).
    // Visibility to epilogue is guaranteed by the K-loop's __syncthreads (Kdim >= 128).
    if (MODE == 3 && tid < 128) {
        const int q = m0 + tid;
        const int nc = 2 * ((q >> 7) + 1);
        float l = 0.f;
        for (int c = 0; c < nc; ++c) l += Pl_in[(size_t)(bz * NSEQ + q) * 32 + c];
        rinv_lds[tid] = 1.0f / l;
    }

    const __hip_bfloat16* asrc[4];
    const __hip_bfloat16* bsrc[4];
#pragma unroll
    for (int r = 0; r < 4; ++r) {
        const int chunk = r * 256 + tid;
        const int row = chunk >> 3, slot = chunk & 7;
        const int col = ((slot ^ (row & 7)) * 8);
        asrc[r] = Ab + (size_t)(m0 + row) * lda + col;
        bsrc[r] = Bb + (size_t)(n0 + row) * ldb + col;
    }

    const int sw = lr & 7;
    const int slotA0 = (lk ^ sw) * 16, slotA1 = ((4 + lk) ^ sw) * 16;

    f32x4 acc[4][4] = {};

    for (int k0 = 0; k0 < Kdim; k0 += 64) {
#pragma unroll
        for (int r = 0; r < 4; ++r) {
            gload_lds16(asrc[r], (char*)As + r * 4096 + wid * 1024);
            gload_lds16(bsrc[r], (char*)Bs + r * 4096 + wid * 1024);
            asrc[r] += 64; bsrc[r] += 64;
        }
        __syncthreads();

        bf16x8 af0[4], bf0[4], af1[4], bf1[4];
#pragma unroll
        for (int m = 0; m < 4; ++m) {
            const int ra = (wm * 64 + m * 16 + lr) * 128;
            const int rb = (wn * 64 + m * 16 + lr) * 128;
            af0[m] = *reinterpret_cast<const bf16x8*>((const char*)As + ra + slotA0);
            af1[m] = *reinterpret_cast<const bf16x8*>((const char*)As + ra + slotA1);
            bf0[m] = *reinterpret_cast<const bf16x8*>((const char*)Bs + rb + slotA0);
            bf1[m] = *reinterpret_cast<const bf16x8*>((const char*)Bs + rb + slotA1);
        }
#pragma unroll
        for (int m = 0; m < 4; ++m)
#pragma unroll
            for (int n = 0; n < 4; ++n)
                acc[m][n] = __builtin_amdgcn_mfma_f32_16x16x32_bf16(af0[m], bf0[n], acc[m][n], 0, 0, 0);
#pragma unroll
        for (int m = 0; m < 4; ++m)
#pragma unroll
            for (int n = 0; n < 4; ++n)
                acc[m][n] = __builtin_amdgcn_mfma_f32_16x16x32_bf16(af1[m], bf1[n], acc[m][n], 0, 0, 0);
        __syncthreads();
    }

    if (MODE == 2) {
        // max-free softmax numerator: p = exp(s/32) (causal-masked -> 0), stored bf16
        unsigned short* P = (unsigned short*)o0 + (size_t)bz * NSEQ * NSEQ;
#pragma unroll
        for (int m = 0; m < 4; ++m)
#pragma unroll
            for (int n = 0; n < 4; ++n) {
                const int rbase = m0 + wm * 64 + m * 16 + lk * 4;
                const int cbase = n0 + wn * 64 + n * 16 + lr;
#pragma unroll
                for (int j = 0; j < 4; ++j) {
                    float p = (cbase > rbase + j) ? 0.0f
                              : __expf(acc[m][n][j] * 0.03125f);   // 1/sqrt(1024)
                    acc[m][n][j] = p;
                    P[(size_t)(rbase + j) * NSEQ + cbase] = f2bf(p);
                }
            }
        // per-(row, 64-col slice) partial row sums; slice index = by*2 + wn
        float* Pl = (float*)o1;
        const int pcol = by * 2 + wn;
#pragma unroll
        for (int m = 0; m < 4; ++m)
#pragma unroll
            for (int j = 0; j < 4; ++j) {
                float sm = (acc[m][0][j] + acc[m][1][j]) + (acc[m][2][j] + acc[m][3][j]);
#pragma unroll
                for (int w = 1; w < 16; w <<= 1) sm += __shfl_xor(sm, w, 64);
                if (lr == 0) {
                    const int row = bz * NSEQ + m0 + wm * 64 + m * 16 + lk * 4 + j;
                    Pl[row * 32 + pcol] = sm;
                }
            }
    } else {
        float* O = (float*)o0 + (size_t)bz * NSEQ * D_;
#pragma unroll
        for (int m = 0; m < 4; ++m)
#pragma unroll
            for (int n = 0; n < 4; ++n) {
                const int rbase = m0 + wm * 64 + m * 16 + lk * 4;
                const int cbase = n0 + wn * 64 + n * 16 + lr;
#pragma unroll
                for (int j = 0; j < 4; ++j)
                    O[(size_t)(rbase + j) * D_ + cbase] =
                        acc[m][n][j] * rinv_lds[rbase + j - m0];
            }
    }
}

extern "C" void kernel_launch(void* const* d_in, const int* in_sizes, int n_in,
                              void* d_out, int out_size, void* d_ws, size_t ws_size,
                              hipStream_t stream) {
    const float* x  = (const float*)d_in[0];
    const float* Wq = (const float*)d_in[1];
    const float* Wk = (const float*)d_in[2];
    const float* Wv = (const float*)d_in[3];

    char* ws = (char*)d_ws;
    unsigned short* P    = (unsigned short*)(ws);               // 32 MiB (bf16)
    __hip_bfloat16* Xb   = (__hip_bfloat16*)(ws + 67108864);    // 16 MiB (dead after QKV)
    __hip_bfloat16* Q    = (__hip_bfloat16*)(ws + 83886080);    // 16 MiB
    __hip_bfloat16* K    = (__hip_bfloat16*)(ws + 100663296);   // 16 MiB
    __hip_bfloat16* Vt   = (__hip_bfloat16*)(ws + 117440512);   // 16 MiB
    __hip_bfloat16* Wt   = (__hip_bfloat16*)(ws + 134217728);   // 6 MiB
    float*  Pl = (float*)(ws + 67108864);                       // 1 MiB (overlays Xb)

    // fused prep: x->bf16 (8192 blocks) + W transpose (3072 blocks)
    prep<<<11264, 256, 0, stream>>>(x, Wq, Wk, Wv, Xb, Wt);

    // fused QKV: 256x128 triple-buffered pipeline (r8 structure), bx-inner grid
    gemm_qkv<<<dim3(32, 24), 512, 147456, stream>>>(Xb, Wt, Q, K, Vt);

    // scores -> P = exp(s/32) + partial row sums (flat lower-triangle enumeration)
    gemm128<2><<<dim3(544), 256, 0, stream>>>(Q, 1024, K, 1024, P, Pl, nullptr);
    // PV (flat grid, anti-correlated Kdim pairing); A = P bf16 (lda 2048);
    // rinv computed per-block from Pl (sum_merge fused away)
    gemm128<3><<<dim3(512), 256, 0, stream>>>((const __hip_bfloat16*)P, 2048, Vt, 2048,
                                              d_out, nullptr, Pl);
}